// Round 7
// baseline (114.688 us; speedup 1.0000x reference)
//
#include <hip/hip_runtime.h>
#include <hip/hip_bf16.h>
#include <hip/hip_cooperative_groups.h>

namespace cg = cooperative_groups;

// MPNN fused pipeline, R18: single cooperative kernel.
// Evidence: R14/R15b/R17b (226MB vs 123MB staged, 64^2 vs 128^2 tiles) all
// land at 113-115us while ideal kernel work is ~30us -> the ~80us residual is
// serial dispatch-boundary cost (launch gaps + per-kernel device-scope L2
// flush across 8 non-coherent XCDs), not kernel time.  Fix: fuse the 5-deep
// chain into ONE hipLaunchCooperativeKernel dispatch with 4 grid.sync()s:
//   P0 prep (h bf16+swz, weight transposes, Nacc zero)
//   P1 e/G GEMMs   (512 x 128^2-tile jobs, R17b job0 verbatim)
//   P2 Nacc += G^T e /256 (128 split-K jobs, R17b job1 verbatim, atomics)
//   P3 convert_n   (64 jobs, verbatim)
//   P4 final GEMM  (512 x 64^2-tile jobs, R14's proven 64^2 core; k-order
//                   per output element identical -> same rounding)
// Grid size from hipOccupancyMaxActiveBlocksPerMultiprocessor (host query,
// capture-safe); on any launch failure, fall back to the byte-identical
// R17b 5-dispatch path (proven 114us / absmax 0.5).

typedef short bf16x8  __attribute__((ext_vector_type(8)));
typedef short short4v __attribute__((ext_vector_type(4)));
typedef float f32x4   __attribute__((ext_vector_type(4)));

__device__ inline short f2bf(float x) {                // fp32 -> bf16 RNE
    unsigned u = __builtin_bit_cast(unsigned, x);
    return (short)((u + 0x7fffu + ((u >> 16) & 1u)) >> 16);
}
__device__ inline float bf2f(short b) {
    return __builtin_bit_cast(float, (unsigned)((unsigned short)b) << 16);
}
__device__ inline void cp16_async(const char* g, char* l) {
    __builtin_amdgcn_global_load_lds(
        (const __attribute__((address_space(1))) unsigned int*)g,
        (__attribute__((address_space(3))) unsigned int*)l, 16, 0, 0);
}

// --------------------------------------------------------------- core128
// 128x128-tile, BK=64, 4 waves 2x2, double-buffered DMA staging.
// Byte-identical LDS layout to R17b's gemm_all: buf b A at Sf+b*16384,
// B at Sf+b*16384+8192 (shorts).  Ends with __syncthreads().
__device__ __forceinline__ void core128(
    const short* __restrict__ Ap, int lda, const short* __restrict__ Bp, int ldb,
    int kbeg, int kend, int m0, int n0, short* Sf, f32x4 acc[4][4], int t)
{
    const int l = t & 63, lr = l & 15, q = l >> 4;
    const int w = t >> 6, wm = w >> 1, wn = w & 1;
    const int wub = t & ~63;

    auto stage = [&](int buf, int k0) {
        #pragma unroll
        for (int it = 0; it < 4; ++it) {
            int idx = it * 256 + t, r = idx >> 3, s = idx & 7;
            cp16_async((const char*)(Ap + (size_t)(m0 + r) * lda + k0) + s * 16,
                       (char*)(Sf + buf * 16384) + (size_t)(it * 256 + wub) * 16);
        }
        #pragma unroll
        for (int it = 0; it < 4; ++it) {
            int idx = it * 256 + t, r = idx >> 3, s = idx & 7;
            cp16_async((const char*)(Bp + (size_t)(n0 + r) * ldb + k0) + s * 16,
                       (char*)(Sf + buf * 16384 + 8192) + (size_t)(it * 256 + wub) * 16);
        }
    };

    stage(0, kbeg);
    __syncthreads();
    int cur = 0;
    for (int k0 = kbeg; k0 < kend; k0 += 64) {
        if (k0 + 64 < kend) stage(cur ^ 1, k0 + 64);
        const short* As = Sf + cur * 16384;
        const short* Bs = As + 8192;
        #pragma unroll
        for (int ks = 0; ks < 2; ++ks) {
            bf16x8 af[4], bfr[4];
            #pragma unroll
            for (int mt = 0; mt < 4; ++mt) {
                int ar = wm * 64 + mt * 16 + lr;
                af[mt] = *(const bf16x8*)&As[ar * 64 + (((ks*4 + q) ^ (ar & 7)) << 3)];
            }
            #pragma unroll
            for (int nt = 0; nt < 4; ++nt) {
                int br = wn * 64 + nt * 16 + lr;
                bfr[nt] = *(const bf16x8*)&Bs[br * 64 + (((ks*4 + q) ^ (br & 7)) << 3)];
            }
            #pragma unroll
            for (int mt = 0; mt < 4; ++mt)
                #pragma unroll
                for (int nt = 0; nt < 4; ++nt)
                    acc[mt][nt] = __builtin_amdgcn_mfma_f32_16x16x32_bf16(
                        af[mt], bfr[nt], acc[mt][nt], 0, 0, 0);
        }
        __syncthreads();
        cur ^= 1;
    }
}

// ---------------------------------------------------------- mpnn_fused
__global__ __launch_bounds__(256, 1)
void mpnn_fused(int NB, const float* __restrict__ X,
                const float* __restrict__ W1, const float* __restrict__ b1v,
                const float* __restrict__ W2, const float* __restrict__ b2v,
                const float* __restrict__ Wo, const float* __restrict__ bov,
                short* __restrict__ h, short* __restrict__ e1t, short* __restrict__ e2t,
                short* __restrict__ G1t, short* __restrict__ G2t,
                short* __restrict__ Wt1, short* __restrict__ Wt2,
                short* __restrict__ Wto1, short* __restrict__ Wto2,
                short* __restrict__ Bt4, float* __restrict__ Nacc,
                float* __restrict__ outf)
{
    cg::grid_group gg = cg::this_grid();
    const int b = blockIdx.x, t = threadIdx.x;
    const int l = t & 63, lr = l & 15, q = l >> 4;
    const int w = t >> 6, wm = w >> 1, wn = w & 1, wub = t & ~63;

    __shared__ __attribute__((aligned(16))) short S[4][8192];  // 64 KB flat
    short* Sf = &S[0][0];

    // ================= P0: prep =================
    {
        // h[:,0:256] = bf16(X), granule-swizzled (values identical to R17b)
        for (int gi = b * 256 + t; gi < 262144; gi += NB * 256) {
            int r = gi >> 5, g = gi & 31;
            const float* xp = X + (size_t)r * 256 + g * 8;
            f32x4 va = *(const f32x4*)xp;
            f32x4 vb = *(const f32x4*)(xp + 4);
            bf16x8 pk;
            pk[0] = f2bf(va[0]); pk[1] = f2bf(va[1]);
            pk[2] = f2bf(va[2]); pk[3] = f2bf(va[3]);
            pk[4] = f2bf(vb[0]); pk[5] = f2bf(vb[1]);
            pk[6] = f2bf(vb[2]); pk[7] = f2bf(vb[3]);
            int slot = (g & 7) ^ (r & 7);
            *(bf16x8*)(h + (size_t)r * 768 + (g >> 3) * 64 + slot * 8) = pk;
        }
        // Nacc zero
        for (int i = b * 256 + t; i < 131072; i += NB * 256) Nacc[i] = 0.f;
        // weight 32x32 transpose tiles (320 jobs), LDS tile aliased into S
        short (*tile)[33] = (short(*)[33])Sf;
        const int tx = t & 31, ty = t >> 5;
        for (int tw = b; tw < 320; tw += NB) {
            const float* src; short* dst; int ldwt, dk0, kx, ny;
            if (tw < 64)       { src = W1; dst = Wt1; ldwt = 256;
                                 kx = tw >> 3; ny = tw & 7; dk0 = kx * 32; }
            else if (tw < 128) { int u = tw - 64; src = W2; dst = Wt2; ldwt = 256;
                                 kx = u >> 3; ny = u & 7; dk0 = kx * 32; }
            else               { int u = tw - 128; int g = u >> 6; int rem = u & 63;
                                 kx = rem >> 3; ny = rem & 7;
                                 src = Wo + (size_t)g * 65536;
                                 if (g == 0) { dst = Bt4; ldwt = 768; dk0 = kx * 32; }
                                 else        { dst = (g == 1) ? Wto1 : Wto2;
                                               ldwt = 256; dk0 = kx * 32; } }
            const int k0l = kx * 32, n0 = ny * 32;
            __syncthreads();
            #pragma unroll
            for (int i = 0; i < 4; ++i) {
                int row = ty + i * 8;
                tile[row][tx] = f2bf(src[(size_t)(k0l + row) * 256 + n0 + tx]);
            }
            __syncthreads();
            #pragma unroll
            for (int i = 0; i < 4; ++i) {
                int row = ty + i * 8;
                int n = n0 + row;
                int slot = ((((dk0 & 32) + tx) >> 3) ^ (n & 7));
                dst[(size_t)n * ldwt + (dk0 & ~63) + slot * 8 + (tx & 7)] =
                    tile[tx][row];
            }
        }
    }
    gg.sync();

    // ================= P1: e/G GEMMs (512 jobs, R17b job0) =================
    for (int job = b; job < 512; job += NB) {
        const int z = job >> 7, rem = job & 127;
        const int m0 = (rem & 63) * 128, n0 = (rem >> 6) * 128;
        const int mode = (z < 2) ? 1 : 3;
        const int sim = z & 1;
        const short* Bp   = (z == 0) ? Wt1 : (z == 1) ? Wt2 : (z == 2) ? Wto1 : Wto2;
        const float* bias = (z == 0) ? b1v : (z == 1) ? b2v : nullptr;
        short* et         = (z == 0) ? e1t : (z == 1) ? e2t : (z == 2) ? G1t : G2t;

        __syncthreads();                      // guard S vs previous job/phase
        f32x4 acc[4][4];
        #pragma unroll
        for (int i = 0; i < 4; ++i)
            #pragma unroll
            for (int j = 0; j < 4; ++j) acc[i][j] = f32x4{0.f, 0.f, 0.f, 0.f};
        core128(h, 768, Bp, 256, 0, 256, m0, n0, Sf, acc, t);

        // epilogue (R17b mode 1/3 verbatim): Hs row-major, Ts transposed+swz
        short* Hs = Sf;                       // [128][128]
        short* Ts = Sf + 16384;               // [128][128]
        #pragma unroll
        for (int mt = 0; mt < 4; ++mt)
            #pragma unroll
            for (int nt = 0; nt < 4; ++nt) {
                int n_loc = wn * 64 + nt * 16 + lr;
                float bb = (mode == 1) ? bias[n0 + n_loc] : 0.f;
                short vb[4];
                #pragma unroll
                for (int r = 0; r < 4; ++r) {
                    float v = acc[mt][nt][r] + bb;
                    if (mode == 1) v = v > 0.f ? v : 0.f;
                    vb[r] = f2bf(v);
                    if (mode == 1) {
                        int m_loc = wm * 64 + mt * 16 + q * 4 + r;
                        Hs[m_loc * 128 + n_loc] = vb[r];
                    }
                }
                int gm = wm * 8 + mt * 2 + (q >> 1);
                short4v pk = { vb[0], vb[1], vb[2], vb[3] };
                *(short4v*)&Ts[n_loc * 128 + ((gm >> 3) << 6)
                               + (((gm & 7) ^ (n_loc & 7)) << 3) + ((q & 1) << 2)] = pk;
            }
        __syncthreads();
        if (mode == 1) {
            const int cb = 256 + sim * 256 + n0;
            for (int i = t; i < 2048; i += 256) {
                int ml = i >> 4, g = i & 15;
                bf16x8 hv = *(const bf16x8*)&Hs[ml * 128 + g * 8];
                *(bf16x8*)(h + (size_t)(m0 + ml) * 768 + cb + ((g >> 3) << 6)
                           + (((g & 7) ^ (ml & 7)) << 3)) = hv;
            }
        }
        for (int i = t; i < 2048; i += 256) {
            int nl = i >> 4, s = i & 15;
            bf16x8 tv = *(const bf16x8*)&Ts[nl * 128 + s * 8];
            *(bf16x8*)(et + (size_t)(n0 + nl) * 8192 + m0 + s * 8) = tv;
        }
    }
    gg.sync();

    // ================= P2: Nacc split-K (128 jobs, R17b job1) =============
    for (int job = b; job < 128; job += NB) {
        const int bx = job & 1, by = (job >> 1) & 1, bz = job >> 2;
        const int sim = bz & 1, split = bz >> 1;
        const int kbeg = split * 512, kend = kbeg + 512;
        const int m0 = bx * 128, n0 = by * 128;
        const short* Ap = sim ? G2t : G1t;
        const short* Bp = sim ? e2t : e1t;

        __syncthreads();
        f32x4 acc[4][4];
        #pragma unroll
        for (int i = 0; i < 4; ++i)
            #pragma unroll
            for (int j = 0; j < 4; ++j) acc[i][j] = f32x4{0.f, 0.f, 0.f, 0.f};
        core128(Ap, 8192, Bp, 8192, kbeg, kend, m0, n0, Sf, acc, t);

        float* Mo = Nacc + (size_t)sim * 65536;
        #pragma unroll
        for (int mt = 0; mt < 4; ++mt)
            #pragma unroll
            for (int nt = 0; nt < 4; ++nt)
                #pragma unroll
                for (int r = 0; r < 4; ++r) {
                    int m = m0 + wm * 64 + mt * 16 + q * 4 + r;
                    int n = n0 + wn * 64 + nt * 16 + lr;
                    atomicAdd(&Mo[(size_t)m * 256 + n],
                              acc[mt][nt][r] * (1.0f / 256.0f));
                }
    }
    gg.sync();

    // ================= P3: convert N -> Bt4 (64 jobs, verbatim) ===========
    for (int job = b; job < 64; job += NB) {
        int gid = job * 256 + t;               // 0..16383
        int sim = gid >> 13, rem = gid & 8191;
        int n = rem >> 5, g = rem & 31;
        const float* np = Nacc + (size_t)sim * 65536 + (size_t)n * 256 + g * 8;
        f32x4 va = *(const f32x4*)np;
        f32x4 vb = *(const f32x4*)(np + 4);
        bf16x8 pk;
        pk[0] = f2bf(va[0]); pk[1] = f2bf(va[1]);
        pk[2] = f2bf(va[2]); pk[3] = f2bf(va[3]);
        pk[4] = f2bf(vb[0]); pk[5] = f2bf(vb[1]);
        pk[6] = f2bf(vb[2]); pk[7] = f2bf(vb[3]);
        int k = 256 + sim * 256 + g * 8;
        int slot = (g & 7) ^ (n & 7);
        *(bf16x8*)(Bt4 + (size_t)n * 768 + (k & ~63) + slot * 8) = pk;
    }
    gg.sync();

    // ================= P4: final GEMM, 64^2 tiles (512 jobs, R14 core) ====
    {
        short* As = Sf;                        // 64*64 shorts
        short* Bs = Sf + 4096;
        for (int job = b; job < 512; job += NB) {
            const int m0 = (job >> 2) * 64, n0 = (job & 3) * 64;
            f32x4 acc4[4];
            #pragma unroll
            for (int i = 0; i < 4; ++i) acc4[i] = f32x4{0.f, 0.f, 0.f, 0.f};
            for (int k0 = 0; k0 < 768; k0 += 64) {
                __syncthreads();
                #pragma unroll
                for (int it = 0; it < 2; ++it) {
                    int idx = it * 256 + t, r = idx >> 3, s = idx & 7;
                    cp16_async((const char*)(h + (size_t)(m0 + r) * 768 + k0) + s * 16,
                               (char*)As + (size_t)(it * 256 + wub) * 16);
                }
                #pragma unroll
                for (int it = 0; it < 2; ++it) {
                    int idx = it * 256 + t, r = idx >> 3, s = idx & 7;
                    cp16_async((const char*)(Bt4 + (size_t)(n0 + r) * 768 + k0) + s * 16,
                               (char*)Bs + (size_t)(it * 256 + wub) * 16);
                }
                __syncthreads();
                #pragma unroll
                for (int ks = 0; ks < 2; ++ks) {
                    int arow = w * 16 + lr;
                    bf16x8 af = *(const bf16x8*)
                        &As[arow * 64 + (((ks*4 + q) ^ (arow & 7)) << 3)];
                    #pragma unroll
                    for (int nt = 0; nt < 4; ++nt) {
                        int brow = nt * 16 + lr;
                        bf16x8 bfg = *(const bf16x8*)
                            &Bs[brow * 64 + (((ks*4 + q) ^ (brow & 7)) << 3)];
                        acc4[nt] = __builtin_amdgcn_mfma_f32_16x16x32_bf16(
                            af, bfg, acc4[nt], 0, 0, 0);
                    }
                }
            }
            #pragma unroll
            for (int nt = 0; nt < 4; ++nt)
                #pragma unroll
                for (int r = 0; r < 4; ++r) {
                    int m = m0 + w * 16 + q * 4 + r;
                    int n = n0 + nt * 16 + lr;
                    float v = acc4[nt][r] + bov[n];
                    outf[(size_t)m * 256 + n] = v > 0.f ? v : 0.f;
                }
        }
    }
}

// ======================================================================
// Fallback path: R17b 5-dispatch pipeline, verbatim (proven 114us, 0.5).
// ======================================================================

__global__ void prep_all(const float* __restrict__ X, short* __restrict__ h,
                         const float* __restrict__ W1, const float* __restrict__ W2,
                         const float* __restrict__ Wo,
                         short* __restrict__ Wt1, short* __restrict__ Wt2,
                         short* __restrict__ Wto1, short* __restrict__ Wto2,
                         short* __restrict__ Bt4, float* __restrict__ Nacc)
{
    __shared__ short tile[32][33];
    const int tx = threadIdx.x, ty = threadIdx.y;      // 32 x 8
    if (blockIdx.y < 8) {
        const int r0 = blockIdx.x * 32, c0 = blockIdx.y * 32;
        #pragma unroll
        for (int i = 0; i < 4; ++i) {
            int row = ty + i * 8;
            short b = f2bf(X[(size_t)(r0 + row) * 256 + c0 + tx]);
            int slot = ((((c0 & 32) + tx) >> 3) ^ ((r0 + row) & 7));
            h[(size_t)(r0 + row) * 768 + (c0 & ~63) + slot * 8 + (tx & 7)] = b;
        }
        return;
    }
    int tw = (blockIdx.y - 8) * 256 + blockIdx.x;
    if (tw >= 320) {
        int i0 = (tw - 320) * 256 + ty * 32 + tx;
        for (int i = i0; i < 131072; i += 49152) Nacc[i] = 0.f;
        return;
    }
    const float* src; short* dst; int ldwt, dk0, kx, ny;
    if (tw < 64)       { src = W1; dst = Wt1; ldwt = 256;
                         kx = tw >> 3; ny = tw & 7; dk0 = kx * 32; }
    else if (tw < 128) { int u = tw - 64; src = W2; dst = Wt2; ldwt = 256;
                         kx = u >> 3; ny = u & 7; dk0 = kx * 32; }
    else               { int u = tw - 128; int g = u >> 6; int rem = u & 63;
                         kx = rem >> 3; ny = rem & 7;
                         src = Wo + (size_t)g * 65536;
                         if (g == 0) { dst = Bt4; ldwt = 768; dk0 = kx * 32; }
                         else        { dst = (g == 1) ? Wto1 : Wto2;
                                       ldwt = 256; dk0 = kx * 32; } }
    const int k0l = kx * 32, n0 = ny * 32;
    #pragma unroll
    for (int i = 0; i < 4; ++i) {
        int row = ty + i * 8;
        tile[row][tx] = f2bf(src[(size_t)(k0l + row) * 256 + n0 + tx]);
    }
    __syncthreads();
    #pragma unroll
    for (int i = 0; i < 4; ++i) {
        int row = ty + i * 8;
        int n = n0 + row;
        int slot = ((((dk0 & 32) + tx) >> 3) ^ (n & 7));
        dst[(size_t)n * ldwt + (dk0 & ~63) + slot * 8 + (tx & 7)] = tile[tx][row];
    }
}

__global__ __launch_bounds__(256, 1)
void gemm_all(int job, short* __restrict__ h,
              const short* __restrict__ Wt1, const short* __restrict__ Wt2,
              const short* __restrict__ Wto1, const short* __restrict__ Wto2,
              const short* __restrict__ Bt4,
              const float* __restrict__ b1, const float* __restrict__ b2,
              const float* __restrict__ bo,
              short* __restrict__ e1t, short* __restrict__ e2t,
              short* __restrict__ G1t, short* __restrict__ G2t,
              float* __restrict__ Nacc, float* __restrict__ outf)
{
    const int z = blockIdx.z;
    int mode, sim = 0, kbeg = 0, kend, lda, ldb;
    const short *Ap, *Bp;
    const float* bias = nullptr;
    short* et = nullptr;
    if (job == 0) {
        Ap = h; lda = 768; kend = 256; ldb = 256;
        if (z < 2) { mode = 1; sim = z;     Bp = z ? Wt2 : Wt1;
                     bias = z ? b2 : b1;    et = z ? e2t : e1t; }
        else       { mode = 3; sim = z - 2; Bp = sim ? Wto2 : Wto1;
                     et = sim ? G2t : G1t; }
    } else if (job == 1) {
        mode = 2; sim = z & 1;
        kbeg = (z >> 1) * 512; kend = kbeg + 512;
        Ap = sim ? G2t : G1t; lda = 8192;
        Bp = sim ? e2t : e1t; ldb = 8192;
    } else {
        mode = 0; Ap = h; lda = 768; kend = 768;
        Bp = Bt4; ldb = 768; bias = bo;
    }

    const int m0 = blockIdx.x * 128, n0 = blockIdx.y * 128;
    const int t = threadIdx.x;
    const int l = t & 63, lr = l & 15, q = l >> 4;
    const int w = t >> 6, wm = w >> 1, wn = w & 1;

    __shared__ __attribute__((aligned(16))) short S[4][8192];
    short* Sf = &S[0][0];

    f32x4 acc[4][4];
    #pragma unroll
    for (int i = 0; i < 4; ++i)
        #pragma unroll
        for (int j = 0; j < 4; ++j) acc[i][j] = f32x4{0.f, 0.f, 0.f, 0.f};

    core128(Ap, lda, Bp, ldb, kbeg, kend, m0, n0, Sf, acc, t);

    if (mode == 0) {
        #pragma unroll
        for (int mt = 0; mt < 4; ++mt)
            #pragma unroll
            for (int nt = 0; nt < 4; ++nt)
                #pragma unroll
                for (int r = 0; r < 4; ++r) {
                    int m = m0 + wm * 64 + mt * 16 + q * 4 + r;
                    int n = n0 + wn * 64 + nt * 16 + lr;
                    float v = acc[mt][nt][r] + bias[n];
                    outf[(size_t)m * 256 + n] = v > 0.f ? v : 0.f;
                }
    } else if (mode == 2) {
        float* Mo = Nacc + (size_t)sim * 65536;
        #pragma unroll
        for (int mt = 0; mt < 4; ++mt)
            #pragma unroll
            for (int nt = 0; nt < 4; ++nt)
                #pragma unroll
                for (int r = 0; r < 4; ++r) {
                    int m = m0 + wm * 64 + mt * 16 + q * 4 + r;
                    int n = n0 + wn * 64 + nt * 16 + lr;
                    atomicAdd(&Mo[(size_t)m * 256 + n],
                              acc[mt][nt][r] * (1.0f / 256.0f));
                }
    } else {
        short* Hs = Sf;
        short* Ts = Sf + 16384;
        #pragma unroll
        for (int mt = 0; mt < 4; ++mt)
            #pragma unroll
            for (int nt = 0; nt < 4; ++nt) {
                int n_loc = wn * 64 + nt * 16 + lr;
                float bb = (mode == 1) ? bias[n0 + n_loc] : 0.f;
                short vb[4];
                #pragma unroll
                for (int r = 0; r < 4; ++r) {
                    float v = acc[mt][nt][r] + bb;
                    if (mode == 1) v = v > 0.f ? v : 0.f;
                    vb[r] = f2bf(v);
                    if (mode == 1) {
                        int m_loc = wm * 64 + mt * 16 + q * 4 + r;
                        Hs[m_loc * 128 + n_loc] = vb[r];
                    }
                }
                int gm = wm * 8 + mt * 2 + (q >> 1);
                short4v pk = { vb[0], vb[1], vb[2], vb[3] };
                *(short4v*)&Ts[n_loc * 128 + ((gm >> 3) << 6)
                               + (((gm & 7) ^ (n_loc & 7)) << 3) + ((q & 1) << 2)] = pk;
            }
        __syncthreads();
        if (mode == 1) {
            const int cb = 256 + sim * 256 + n0;
            for (int i = t; i < 2048; i += 256) {
                int ml = i >> 4, g = i & 15;
                bf16x8 hv = *(const bf16x8*)&Hs[ml * 128 + g * 8];
                *(bf16x8*)(h + (size_t)(m0 + ml) * 768 + cb + ((g >> 3) << 6)
                           + (((g & 7) ^ (ml & 7)) << 3)) = hv;
            }
        }
        for (int i = t; i < 2048; i += 256) {
            int nl = i >> 4, s = i & 15;
            bf16x8 tv = *(const bf16x8*)&Ts[nl * 128 + s * 8];
            *(bf16x8*)(et + (size_t)(n0 + nl) * 8192 + m0 + s * 8) = tv;
        }
    }
}

__global__ void convert_n(const float* __restrict__ Nacc, short* __restrict__ Bt4)
{
    int gid = blockIdx.x * 256 + threadIdx.x;
    int sim = gid >> 13, rem = gid & 8191;
    int n = rem >> 5, g = rem & 31;
    const float* np = Nacc + (size_t)sim * 65536 + (size_t)n * 256 + g * 8;
    f32x4 va = *(const f32x4*)np;
    f32x4 vb = *(const f32x4*)(np + 4);
    bf16x8 pk;
    pk[0] = f2bf(va[0]); pk[1] = f2bf(va[1]);
    pk[2] = f2bf(va[2]); pk[3] = f2bf(va[3]);
    pk[4] = f2bf(vb[0]); pk[5] = f2bf(vb[1]);
    pk[6] = f2bf(vb[2]); pk[7] = f2bf(vb[3]);
    int k = 256 + sim * 256 + g * 8;
    int slot = (g & 7) ^ (n & 7);
    *(bf16x8*)(Bt4 + (size_t)n * 768 + (k & ~63) + slot * 8) = pk;
}

// ---------------------------------------------------------------- launch
extern "C" void kernel_launch(void* const* d_in, const int* in_sizes, int n_in,
                              void* d_out, int out_size, void* d_ws, size_t ws_size,
                              hipStream_t stream)
{
    const float* edge_x = (const float*)d_in[0];
    const float* W1 = (const float*)d_in[1];
    const float* b1 = (const float*)d_in[2];
    const float* W2 = (const float*)d_in[3];
    const float* b2 = (const float*)d_in[4];
    const float* Wo = (const float*)d_in[5];
    const float* bo = (const float*)d_in[6];

    char* ws = (char*)d_ws;
    short* h    = (short*)ws;                    // [8192][768] bf16 swz  12,582,912
    short* e1t  = (short*)(ws + 12582912);       // [256][8192] bf16 swz   4,194,304
    short* e2t  = (short*)(ws + 16777216);       // [256][8192] bf16 swz   4,194,304
    short* G1t  = (short*)(ws + 20971520);       // [256][8192] bf16 swz   4,194,304
    short* G2t  = (short*)(ws + 25165824);       // [256][8192] bf16 swz   4,194,304
    short* Wt1  = (short*)(ws + 29360128);       // [256][256]  bf16 swz     131,072
    short* Wt2  = (short*)(ws + 29491200);       // [256][256]  bf16 swz     131,072
    short* Wto1 = (short*)(ws + 29622272);       // [256][256]  bf16 swz     131,072
    short* Wto2 = (short*)(ws + 29753344);       // [256][256]  bf16 swz     131,072
    short* Bt4  = (short*)(ws + 29884416);       // [256][768]  bf16 swz     393,216
    float* Nacc = (float*)(ws + 30277632);       // [2][256][256] fp32       524,288

    float* out = (float*)d_out;

    // ---- primary: single cooperative dispatch ----
    int nbpm = 0;
    hipError_t oe = hipOccupancyMaxActiveBlocksPerMultiprocessor(
        &nbpm, (const void*)mpnn_fused, 256, 0);
    if (oe == hipSuccess && nbpm >= 1) {
        int NB = (nbpm >= 2) ? 512 : 256;
        void* args[] = { &NB, (void*)&edge_x, (void*)&W1, (void*)&b1,
                         (void*)&W2, (void*)&b2, (void*)&Wo, (void*)&bo,
                         (void*)&h, (void*)&e1t, (void*)&e2t, (void*)&G1t,
                         (void*)&G2t, (void*)&Wt1, (void*)&Wt2, (void*)&Wto1,
                         (void*)&Wto2, (void*)&Bt4, (void*)&Nacc, (void*)&out };
        hipError_t le = hipLaunchCooperativeKernel(
            (const void*)mpnn_fused, dim3(NB, 1, 1), dim3(256, 1, 1),
            args, 0, stream);
        if (le == hipSuccess) return;
    }

    // ---- fallback: R17b 5-dispatch pipeline (proven) ----
    prep_all<<<dim3(256, 10), dim3(32, 8), 0, stream>>>(
        edge_x, h, W1, W2, Wo, Wt1, Wt2, Wto1, Wto2, Bt4, Nacc);
    gemm_all<<<dim3(64, 2, 4), 256, 0, stream>>>(
        0, h, Wt1, Wt2, Wto1, Wto2, Bt4, b1, b2, bo,
        e1t, e2t, G1t, G2t, Nacc, out);
    gemm_all<<<dim3(2, 2, 32), 256, 0, stream>>>(
        1, h, Wt1, Wt2, Wto1, Wto2, Bt4, b1, b2, bo,
        e1t, e2t, G1t, G2t, Nacc, out);
    convert_n<<<dim3(64), 256, 0, stream>>>(Nacc, Bt4);
    gemm_all<<<dim3(64, 2, 1), 256, 0, stream>>>(
        2, h, Wt1, Wt2, Wto1, Wto2, Bt4, b1, b2, bo,
        e1t, e2t, G1t, G2t, Nacc, out);
}